// Round 1
// baseline (1027.097 us; speedup 1.0000x reference)
//
#include <hip/hip_runtime.h>

// Problem constants (fixed by setup_inputs)
constexpr int NDA = 10000;   // target graph nodes
constexpr int NQ  = 64;      // query graph nodes
constexpr int CND = 1024;    // candidate set size
constexpr int DIN = 128;     // input feature dim
constexpr int D   = 256;     // hidden dim
constexpr int CAP = 96;      // max nnz per adjacency row (Poisson(20); P(>96) ~ 0)

#define LRELU(x) ((x) >= 0.f ? (x) : 0.01f * (x))

__device__ __forceinline__ float wave_red64(float v) {
#pragma unroll
    for (int o = 32; o; o >>= 1) v += __shfl_down(v, o);
    return v;
}

// ---------------------------------------------------------------------------
// CSR build: one block per row, scan 10000 floats, record nonzero columns.
// values are exactly 0.0/1.0 so column indices suffice.
__global__ __launch_bounds__(256) void build_csr(const float* __restrict__ adj,
                                                 int* __restrict__ cols,
                                                 int* __restrict__ rowcnt) {
    int row = blockIdx.x;
    __shared__ int scnt;
    if (threadIdx.x == 0) scnt = 0;
    __syncthreads();
    const float4* rp = (const float4*)(adj + (size_t)row * NDA);
    for (int i = threadIdx.x; i < NDA / 4; i += 256) {
        float4 v = rp[i];
        if (v.x != 0.f) { int s = atomicAdd(&scnt, 1); if (s < CAP) cols[row * CAP + s] = 4 * i; }
        if (v.y != 0.f) { int s = atomicAdd(&scnt, 1); if (s < CAP) cols[row * CAP + s] = 4 * i + 1; }
        if (v.z != 0.f) { int s = atomicAdd(&scnt, 1); if (s < CAP) cols[row * CAP + s] = 4 * i + 2; }
        if (v.w != 0.f) { int s = atomicAdd(&scnt, 1); if (s < CAP) cols[row * CAP + s] = 4 * i + 3; }
    }
    __syncthreads();
    if (threadIdx.x == 0) rowcnt[row] = min(scnt, CAP);
}

// ---------------------------------------------------------------------------
// Generic fp32 tiled GEMM: C[M,N] = op(A)[M,K] @ B[K,N].
// 64x64 tile, 256 threads, 4x4 per thread. K % 16 == 0, N % 64 == 0 required.
// RELU_A: apply leaky-relu to A elements on load (for att_da1 = lrelu(da1)).
// RELU_C: apply leaky-relu to C on store.
template <bool RELU_A, bool RELU_C>
__global__ __launch_bounds__(256) void gemm64(const float* __restrict__ A,
                                              const float* __restrict__ B,
                                              float* __restrict__ C,
                                              int M, int N, int K) {
    __shared__ float As[16][68];
    __shared__ float Bs[16][68];
    const int bm = blockIdx.x * 64;
    const int bn = blockIdx.y * 64;
    const int tid = threadIdx.x;
    const int tx = tid & 15, ty = tid >> 4;
    float acc[4][4] = {};
    for (int k0 = 0; k0 < K; k0 += 16) {
        {   // A tile 64x16 -> As[k][m]
            int m = tid >> 2;
            int k4 = (tid & 3) * 4;
            float4 v = make_float4(0.f, 0.f, 0.f, 0.f);
            if (bm + m < M) v = *(const float4*)(A + (size_t)(bm + m) * K + k0 + k4);
            if (RELU_A) { v.x = LRELU(v.x); v.y = LRELU(v.y); v.z = LRELU(v.z); v.w = LRELU(v.w); }
            As[k4 + 0][m] = v.x; As[k4 + 1][m] = v.y; As[k4 + 2][m] = v.z; As[k4 + 3][m] = v.w;
        }
        {   // B tile 16x64 -> Bs[k][n]
            int kk = tid >> 4;
            int n4 = (tid & 15) * 4;
            float4 v = *(const float4*)(B + (size_t)(k0 + kk) * N + bn + n4);
            Bs[kk][n4 + 0] = v.x; Bs[kk][n4 + 1] = v.y; Bs[kk][n4 + 2] = v.z; Bs[kk][n4 + 3] = v.w;
        }
        __syncthreads();
#pragma unroll
        for (int kk = 0; kk < 16; kk++) {
            float av[4], bv[4];
#pragma unroll
            for (int i = 0; i < 4; i++) av[i] = As[kk][ty * 4 + i];
#pragma unroll
            for (int j = 0; j < 4; j++) bv[j] = Bs[kk][tx * 4 + j];
#pragma unroll
            for (int i = 0; i < 4; i++)
#pragma unroll
                for (int j = 0; j < 4; j++) acc[i][j] += av[i] * bv[j];
        }
        __syncthreads();
    }
#pragma unroll
    for (int i = 0; i < 4; i++) {
        int r = bm + ty * 4 + i;
        if (r < M) {
            float4 v;
            v.x = acc[i][0]; v.y = acc[i][1]; v.z = acc[i][2]; v.w = acc[i][3];
            if (RELU_C) { v.x = LRELU(v.x); v.y = LRELU(v.y); v.z = LRELU(v.z); v.w = LRELU(v.w); }
            *(float4*)(C + (size_t)r * N + bn + tx * 4) = v;
        }
    }
}

// ---------------------------------------------------------------------------
// SpMM via CSR (adjacency values are all 1): out1 = lrelu(sum of X rows),
// optional out2 = lrelu(out1)  (the double-lrelu "att" tensor).
__global__ __launch_bounds__(256) void spmm_csr(const int* __restrict__ cols,
                                                const int* __restrict__ rowcnt,
                                                const float* __restrict__ X,
                                                float* __restrict__ out1,
                                                float* __restrict__ out2) {
    int row = blockIdx.x;
    int d = threadIdx.x;
    int cnt = rowcnt[row];
    __shared__ int sc[CAP];
    if (d < cnt) sc[d] = cols[row * CAP + d];
    __syncthreads();
    float a0 = 0.f, a1 = 0.f, a2 = 0.f, a3 = 0.f;
    int k = 0;
    for (; k + 4 <= cnt; k += 4) {
        a0 += X[(size_t)sc[k + 0] * D + d];
        a1 += X[(size_t)sc[k + 1] * D + d];
        a2 += X[(size_t)sc[k + 2] * D + d];
        a3 += X[(size_t)sc[k + 3] * D + d];
    }
    for (; k < cnt; k++) a0 += X[(size_t)sc[k] * D + d];
    float v = LRELU(a0 + a1 + a2 + a3);
    out1[(size_t)row * D + d] = v;
    if (out2) out2[(size_t)row * D + d] = LRELU(v);
}

// ---------------------------------------------------------------------------
// Row L2 norms of da[cand[b]] (b<CND) and of q rows (b>=CND).
__global__ __launch_bounds__(256) void rownorms_kernel(const float* __restrict__ da,
                                                       const int* __restrict__ cand,
                                                       float* __restrict__ rnc,
                                                       const float* __restrict__ q,
                                                       float* __restrict__ rnq) {
    int b = blockIdx.x;
    const float* src;
    float* dst;
    if (b < CND) { src = da + (size_t)cand[b] * D; dst = rnc + b; }
    else         { src = q + (size_t)(b - CND) * D; dst = rnq + (b - CND); }
    float v = src[threadIdx.x];
    float p = wave_red64(v * v);
    __shared__ float red[4];
    int w = threadIdx.x >> 6, lane = threadIdx.x & 63;
    if (lane == 0) red[w] = p;
    __syncthreads();
    if (threadIdx.x == 0) *dst = sqrtf(red[0] + red[1] + red[2] + red[3]);
}

// ---------------------------------------------------------------------------
// Cosine matrix c[r,cc] = (q_r . a_cand[cc]) / (max(|q_r|,eps)*max(|a|,eps)).
// grid (NQ, CND/256); one thread per (r, cc).
__global__ __launch_bounds__(256) void cosmat_kernel(const float* __restrict__ q,
                                                     const float* __restrict__ rnq,
                                                     const float* __restrict__ da,
                                                     const int* __restrict__ cand,
                                                     const float* __restrict__ rnc,
                                                     float* __restrict__ cm) {
    __shared__ float qs[D];
    int r = blockIdx.x;
    int cc = blockIdx.y * 256 + threadIdx.x;
    qs[threadIdx.x] = q[r * D + threadIdx.x];
    __syncthreads();
    int row = cand[cc];
    const float4* ap = (const float4*)(da + (size_t)row * D);
    float dot = 0.f;
#pragma unroll 8
    for (int k = 0; k < D / 4; k++) {
        float4 v = ap[k];
        dot += qs[4 * k] * v.x + qs[4 * k + 1] * v.y + qs[4 * k + 2] * v.z + qs[4 * k + 3] * v.w;
    }
    float denom = fmaxf(rnq[r], 1e-12f) * fmaxf(rnc[cc], 1e-12f);
    cm[r * CND + cc] = dot / denom;
}

// ---------------------------------------------------------------------------
// h[r,:] = sum_cc cm[r,cc] * da[cand[cc],:]   (grid NQ, 256 threads)
__global__ __launch_bounds__(256) void hq_kernel(const float* __restrict__ cm,
                                                 const float* __restrict__ da,
                                                 const int* __restrict__ cand,
                                                 float* __restrict__ h) {
    __shared__ float swt[CND];
    __shared__ int sci[CND];
    int r = blockIdx.x, d = threadIdx.x;
    for (int s = 0; s < CND / 256; s++) {
        swt[s * 256 + d] = cm[r * CND + s * 256 + d];
        sci[s * 256 + d] = cand[s * 256 + d];
    }
    __syncthreads();
    float a0 = 0.f, a1 = 0.f, a2 = 0.f, a3 = 0.f, a4 = 0.f, a5 = 0.f, a6 = 0.f, a7 = 0.f;
    for (int c = 0; c < CND; c += 8) {
        a0 += swt[c + 0] * da[(size_t)sci[c + 0] * D + d];
        a1 += swt[c + 1] * da[(size_t)sci[c + 1] * D + d];
        a2 += swt[c + 2] * da[(size_t)sci[c + 2] * D + d];
        a3 += swt[c + 3] * da[(size_t)sci[c + 3] * D + d];
        a4 += swt[c + 4] * da[(size_t)sci[c + 4] * D + d];
        a5 += swt[c + 5] * da[(size_t)sci[c + 5] * D + d];
        a6 += swt[c + 6] * da[(size_t)sci[c + 6] * D + d];
        a7 += swt[c + 7] * da[(size_t)sci[c + 7] * D + d];
    }
    h[r * D + d] = ((a0 + a1) + (a2 + a3)) + ((a4 + a5) + (a6 + a7));
}

// ---------------------------------------------------------------------------
// att_q = lrelu(q + h / max(colnorm(h),1e-12)); optionally emb = mean rows,
// emb[256] = |emb|. Single block, thread d owns column d.
__global__ __launch_bounds__(256) void attq_kernel(const float* __restrict__ q,
                                                   const float* __restrict__ h,
                                                   float* __restrict__ attq,
                                                   float* __restrict__ emb) {
    int d = threadIdx.x;
    float hv[NQ];
    float ss = 0.f;
#pragma unroll
    for (int r = 0; r < NQ; r++) {
        hv[r] = h[r * D + d];
        ss += hv[r] * hv[r];
    }
    float inv = 1.f / fmaxf(sqrtf(ss), 1e-12f);
    float es = 0.f;
#pragma unroll
    for (int r = 0; r < NQ; r++) {
        float v = q[r * D + d] + hv[r] * inv;
        v = LRELU(v);
        attq[r * D + d] = v;
        es += v;
    }
    if (emb) {
        float e = es * (1.f / (float)NQ);
        emb[d] = e;
        float p = wave_red64(e * e);
        __shared__ float red[4];
        int w = d >> 6, lane = d & 63;
        if (lane == 0) red[w] = p;
        __syncthreads();
        if (d == 0) emb[D] = sqrtf(red[0] + red[1] + red[2] + red[3]);
    }
}

// ---------------------------------------------------------------------------
// end[i] = (a_i . emb) / max(|a_i|*|emb|, 1e-8); m[i] = end>thr; cnt += m.
// One wave per row; grid NDA/4 blocks.
__global__ __launch_bounds__(256) void end_kernel(const float* __restrict__ A,
                                                  const float* __restrict__ emb,
                                                  const float* __restrict__ thr_p,
                                                  float* __restrict__ endv,
                                                  float* __restrict__ m,
                                                  float* __restrict__ cnt) {
    __shared__ float se[D];
    __shared__ float scnt;
    int d = threadIdx.x;
    se[d] = emb[d];
    if (d == 0) scnt = 0.f;
    __syncthreads();
    float embn = emb[D];
    float thr = *thr_p;
    int w = d >> 6, lane = d & 63;
    int row = blockIdx.x * 4 + w;
    const float* ar = A + (size_t)row * D;
    float num = 0.f, sq = 0.f;
#pragma unroll
    for (int s = 0; s < 4; s++) {
        float v = ar[lane + 64 * s];
        num += v * se[lane + 64 * s];
        sq += v * v;
    }
#pragma unroll
    for (int o = 32; o; o >>= 1) { num += __shfl_down(num, o); sq += __shfl_down(sq, o); }
    if (lane == 0) {
        float den = fmaxf(sqrtf(sq) * embn, 1e-8f);
        float e = num / den;
        endv[row] = e;
        float mv = e > thr ? 1.f : 0.f;
        m[row] = mv;
        if (mv != 0.f) atomicAdd(&scnt, 1.f);
    }
    __syncthreads();
    if (d == 0 && scnt != 0.f) atomicAdd(cnt, scnt);
}

// ---------------------------------------------------------------------------
// G = sum_i m_i a_i a_i^T  (256x256), split-K with atomics.
// grid (16 tiles, 25 row-chunks of 400), 256 threads, 4x4 per thread.
constexpr int GCHUNK = 400;
__global__ __launch_bounds__(256) void G_kernel(const float* __restrict__ A,
                                                const float* __restrict__ m,
                                                float* __restrict__ G) {
    __shared__ float SA[8][64], SB[8][64];
    int ti = blockIdx.x >> 2, tj = blockIdx.x & 3;
    int base = blockIdx.y * GCHUNK;
    int tid = threadIdx.x;
    int tx = tid & 15, ty = tid >> 4;
    float acc[4][4] = {};
    for (int g0 = 0; g0 < GCHUNK; g0 += 8) {
        for (int l = tid; l < 512; l += 256) {
            int rr = l >> 6, c = l & 63;
            int r = base + g0 + rr;
            float mv = m[r];
            SA[rr][c] = A[(size_t)r * D + ti * 64 + c] * mv;
            SB[rr][c] = A[(size_t)r * D + tj * 64 + c];
        }
        __syncthreads();
#pragma unroll
        for (int rr = 0; rr < 8; rr++) {
            float av[4], bv[4];
#pragma unroll
            for (int i = 0; i < 4; i++) av[i] = SA[rr][ty * 4 + i];
#pragma unroll
            for (int j = 0; j < 4; j++) bv[j] = SB[rr][tx * 4 + j];
#pragma unroll
            for (int i = 0; i < 4; i++)
#pragma unroll
                for (int j = 0; j < 4; j++) acc[i][j] += av[i] * bv[j];
        }
        __syncthreads();
    }
#pragma unroll
    for (int i = 0; i < 4; i++)
#pragma unroll
        for (int j = 0; j < 4; j++)
            atomicAdd(&G[(ti * 64 + ty * 4 + i) * D + tj * 64 + tx * 4 + j], acc[i][j]);
}

// ---------------------------------------------------------------------------
// Final reduction over adjacency nonzeros:
//  denom_i = max(sqrt(a_i^T G a_i), 1e-12) = max(sqrt(a_i . H_i), 1e-12)
//  total += sum_{j in row i, m_j} (a_i . a_j) / denom_i    (rows with m_i=1)
//  tr    += (a_i . a_i)/denom_i when adj[i,i]=1
__global__ __launch_bounds__(256) void final_kernel(const int* __restrict__ cols,
                                                    const int* __restrict__ rowcnt,
                                                    const float* __restrict__ m,
                                                    const float* __restrict__ A,
                                                    const float* __restrict__ H,
                                                    double* __restrict__ total,
                                                    double* __restrict__ tr) {
    int i = blockIdx.x;
    if (m[i] == 0.f) return;
    __shared__ float sa[D];
    __shared__ int sc[CAP];
    __shared__ float red[4], red2[4];
    __shared__ float sdenom;
    int d = threadIdx.x;
    float av = A[(size_t)i * D + d];
    sa[d] = av;
    int cnt = rowcnt[i];
    if (d < cnt) sc[d] = cols[i * CAP + d];
    float p = wave_red64(av * H[(size_t)i * D + d]);
    int w = d >> 6, lane = d & 63;
    if (lane == 0) red[w] = p;
    __syncthreads();
    if (d == 0) sdenom = fmaxf(sqrtf(red[0] + red[1] + red[2] + red[3]), 1e-12f);
    __syncthreads();
    float accs = 0.f, acct = 0.f;
    for (int k = w; k < cnt; k += 4) {
        int j = sc[k];
        if (m[j] != 0.f) {     // wave-uniform branch
            const float* aj = A + (size_t)j * D;
            float t = sa[lane] * aj[lane] + sa[lane + 64] * aj[lane + 64]
                    + sa[lane + 128] * aj[lane + 128] + sa[lane + 192] * aj[lane + 192];
            t = wave_red64(t);
            if (lane == 0) { accs += t; if (j == i) acct += t; }
        }
    }
    if (lane == 0) { red[w] = accs; red2[w] = acct; }
    __syncthreads();
    if (d == 0) {
        float s = red[0] + red[1] + red[2] + red[3];
        float t2 = red2[0] + red2[1] + red2[2] + red2[3];
        double inv = 1.0 / (double)sdenom;
        if (s != 0.f) atomicAdd(total, (double)s * inv);
        if (t2 != 0.f) atomicAdd(tr, (double)t2 * inv);
    }
}

// ---------------------------------------------------------------------------
__global__ void scalars_kernel(const float* __restrict__ cnt,
                               const double* __restrict__ total,
                               const double* __restrict__ tr,
                               float* __restrict__ out) {
    float c = *cnt;
    float T = (float)*total;
    float R = (float)*tr;
    bool has = c > 0.f;
    out[0] = has ? (T / fmaxf(c, 1.f)) : 0.f;                       // pre_avg_degree
    out[1] = has ? (2.f * T / (R * (R - 1.f) + 1e-4f)) : 0.f;       // pre_density
    out[2] = has ? R : 0.f;                                          // pre_avg_nodes
}

// ---------------------------------------------------------------------------
extern "C" void kernel_launch(void* const* d_in, const int* in_sizes, int n_in,
                              void* d_out, int out_size, void* d_ws, size_t ws_size,
                              hipStream_t stream) {
    (void)in_sizes; (void)n_in; (void)out_size; (void)ws_size;
    const float* adj  = (const float*)d_in[0];
    const float* Fda  = (const float*)d_in[1];
    const float* Qadj = (const float*)d_in[2];
    const float* Fq   = (const float*)d_in[3];
    const int*   cand = (const int*)d_in[4];
    // d_in[5] candidate_adj: unused by the reference
    const float* thr  = (const float*)d_in[6];
    const float* W1da = (const float*)d_in[7];
    const float* W1q  = (const float*)d_in[8];
    const float* W2da = (const float*)d_in[9];
    const float* W2q  = (const float*)d_in[10];

    float* out = (float*)d_out;
    float* o_end    = out;                       // [10000]
    float* o_attda2 = out + NDA;                 // [10000,256]
    float* o_attq2  = out + NDA + (size_t)NDA * D;       // [64,256]
    float* o_sc     = o_attq2 + NQ * D;          // [3] scalars

    char* w = (char*)d_ws;
    size_t off = 0;
    auto alloc = [&](size_t b) { size_t r = off; off += (b + 255) & ~(size_t)255; return r; };
    float* bufA = (float*)(w + alloc((size_t)NDA * D * 4));   // X1 -> Y2
    float* bufB = (float*)(w + alloc((size_t)NDA * D * 4));   // da1 -> H
    float* bufC = (float*)(w + alloc((size_t)NDA * D * 4));   // da2
    int* colsb   = (int*)(w + alloc((size_t)NDA * CAP * 4));
    int* rowcntb = (int*)(w + alloc((size_t)NDA * 4));
    float* mbuf  = (float*)(w + alloc((size_t)NDA * 4));
    char* zbase = w + alloc(262144 + 256);                    // G + scalar accumulators
    float* Gb    = (float*)zbase;
    float* cntb  = (float*)(zbase + 262144);
    double* totb = (double*)(zbase + 262144 + 8);
    double* trb  = (double*)(zbase + 262144 + 16);
    float* xq   = (float*)(w + alloc((size_t)NQ * D * 4));    // Xq -> Zq
    float* q1b  = (float*)(w + alloc((size_t)NQ * D * 4));
    float* aq1  = (float*)(w + alloc((size_t)NQ * D * 4));
    float* q2b  = (float*)(w + alloc((size_t)NQ * D * 4));
    float* hb   = (float*)(w + alloc((size_t)NQ * D * 4));
    float* cm   = (float*)(w + alloc((size_t)NQ * CND * 4));
    float* rnc  = (float*)(w + alloc((size_t)CND * 4));
    float* rnq  = (float*)(w + alloc((size_t)NQ * 4));
    float* embb = (float*)(w + alloc((size_t)(D + 1) * 4));

    hipMemsetAsync(zbase, 0, 262144 + 256, stream);

    const dim3 gBig((NDA + 63) / 64, D / 64);
    const dim3 gSmall(1, D / 64);

    // Layer 1
    gemm64<false, false><<<gBig, 256, 0, stream>>>(Fda, W1da, bufA, NDA, D, DIN);   // X1
    build_csr<<<NDA, 256, 0, stream>>>(adj, colsb, rowcntb);
    gemm64<false, false><<<gSmall, 256, 0, stream>>>(Fq, W1q, xq, NQ, D, DIN);      // Xq
    gemm64<false, true><<<gSmall, 256, 0, stream>>>(Qadj, xq, q1b, NQ, D, NQ);      // q1
    spmm_csr<<<NDA, 256, 0, stream>>>(colsb, rowcntb, bufA, bufB, (float*)nullptr); // da1
    rownorms_kernel<<<CND + NQ, 256, 0, stream>>>(bufB, cand, rnc, q1b, rnq);
    cosmat_kernel<<<dim3(NQ, CND / 256), 256, 0, stream>>>(q1b, rnq, bufB, cand, rnc, cm);
    hq_kernel<<<NQ, 256, 0, stream>>>(cm, bufB, cand, hb);                           // h1
    attq_kernel<<<1, 256, 0, stream>>>(q1b, hb, aq1, (float*)nullptr);               // att_q1
    // Layer 2
    gemm64<true, false><<<gBig, 256, 0, stream>>>(bufB, W2da, bufA, NDA, D, D);      // Y2 = lrelu(da1)@W2
    gemm64<false, false><<<gSmall, 256, 0, stream>>>(aq1, W2q, xq, NQ, D, D);        // Zq
    gemm64<false, true><<<gSmall, 256, 0, stream>>>(Qadj, xq, q2b, NQ, D, NQ);       // q2
    spmm_csr<<<NDA, 256, 0, stream>>>(colsb, rowcntb, bufA, bufC, o_attda2);         // da2 + att_da2
    rownorms_kernel<<<CND + NQ, 256, 0, stream>>>(bufC, cand, rnc, q2b, rnq);
    cosmat_kernel<<<dim3(NQ, CND / 256), 256, 0, stream>>>(q2b, rnq, bufC, cand, rnc, cm);
    hq_kernel<<<NQ, 256, 0, stream>>>(cm, bufC, cand, hb);                           // h2
    attq_kernel<<<1, 256, 0, stream>>>(q2b, hb, o_attq2, embb);                      // att_q2 + emb
    // Scoring
    end_kernel<<<NDA / 4, 256, 0, stream>>>(o_attda2, embb, thr, o_end, mbuf, cntb);
    G_kernel<<<dim3(16, NDA / GCHUNK), 256, 0, stream>>>(o_attda2, mbuf, Gb);
    gemm64<false, false><<<gBig, 256, 0, stream>>>(o_attda2, Gb, bufB, NDA, D, D);   // H = A@G
    final_kernel<<<NDA, 256, 0, stream>>>(colsb, rowcntb, mbuf, o_attda2, bufB, totb, trb);
    scalars_kernel<<<1, 1, 0, stream>>>(cntb, totb, trb, o_sc);
}